// Round 9
// baseline (397.379 us; speedup 1.0000x reference)
//
#include <hip/hip_runtime.h>
#include <hip/hip_fp16.h>

// layer_3d_dep_53300544143949 — MI355X (gfx950)
// B=64, C=8, O=8, M=32, K=32, NR=8, NT=8. All inputs and output FLOAT32.
// R12 = R11 resubmit (R11 bench was an infra failure: container failed twice,
// kernel never ran).
// R11 structure (coop line abandoned; d_out-resident fp16 cascade, LDS diet):
//   k1a: m-mean reduce, block=(b,c), 1024 thr -> mc (ws, 4MB) + stats zero
//   k1b: in-place P2 transform mc -> a2pre
//   k2:  main fold + attention. Writes pre-BN as fp16 at byte 2e of d_out
//        (64MB staging, low half). LDS: a5 aliased onto qb (q lives in regs
//        before any a5 write; extra barriers guard the alias) -> 25.2KB.
//   k3_copy: staging bytes [0,1MiB) (fp16 of e<512Ki) -> ws mcab (dead after k2)
//   k3_slice xN (descending): slice [n,2n) reads fp16 bytes [2n,4n), writes f32
//        bytes [4n,8n) — disjoint within launch; later launches only clobber
//        consumed staging. Slices: 16Mi,8Mi,4Mi,2Mi,1Mi,512Ki, then tail
//        [0,512Ki) from ws. NT stores on final f32.
// ws: [0,256) stats | [256, 256+4MB) mc/a2pre (reused as fp16 tail staging)

using u16 = unsigned short;
using u32 = unsigned int;
typedef float f32x4 __attribute__((ext_vector_type(4)));

#define NTOT 33554432u

__device__ __forceinline__ void ld8f(const float* p, float* f) {
  float4 a = *(const float4*)p;
  float4 b = *(const float4*)(p + 4);
  f[0] = a.x; f[1] = a.y; f[2] = a.z; f[3] = a.w;
  f[4] = b.x; f[5] = b.y; f[6] = b.z; f[7] = b.w;
}
__device__ __forceinline__ void st8f(float* p, const float* f) {
  *(float4*)p = make_float4(f[0], f[1], f[2], f[3]);
  *(float4*)(p + 4) = make_float4(f[4], f[5], f[6], f[7]);
}
__device__ __forceinline__ void st8f_nt(float* p, const float* f) {
  f32x4 a = {f[0], f[1], f[2], f[3]};
  f32x4 b = {f[4], f[5], f[6], f[7]};
  __builtin_nontemporal_store(a, (f32x4*)p);
  __builtin_nontemporal_store(b, (f32x4*)(p + 4));
}
__device__ __forceinline__ u16 f2h(float f) {
  __half h = __float2half_rn(f);
  return *(u16*)&h;
}
__device__ __forceinline__ float h2f(u16 x) {
  __half h = *(__half*)&x;
  return __half2float(h);
}
__device__ __forceinline__ float fast_tanh(float x) {
  float e = __expf(2.0f * x);
  return 1.0f - 2.0f / (e + 1.0f);
}

// ---------------- k1a: m-mean reduce (1024 thr, LDS reduce) ----------------
__global__ __launch_bounds__(1024) void k1a_mmean(
    const float* __restrict__ A, float* __restrict__ mcab,
    float* __restrict__ stats) {
  __shared__ float red[4][256][9];
  const int b = blockIdx.x >> 3;
  const int c = blockIdx.x & 7;
  const int tid = threadIdx.x;
  if (blockIdx.x == 0 && tid < 16) stats[tid] = 0.0f;
  const int mh = tid >> 8;
  const int jt = tid & 255;
  const float* base = A + (size_t)(b * 8 + c) * 65536 + (size_t)mh * 8 * 2048 + jt * 8;
  float acc[8];
#pragma unroll
  for (int t = 0; t < 8; ++t) acc[t] = 0.0f;
#pragma unroll
  for (int m = 0; m < 8; ++m) {
    float ar[8];
    ld8f(base + m * 2048, ar);
#pragma unroll
    for (int t = 0; t < 8; ++t) acc[t] += ar[t];
  }
#pragma unroll
  for (int t = 0; t < 8; ++t) red[mh][jt][t] = acc[t];
  __syncthreads();
  if (mh == 0) {
    float s[8];
#pragma unroll
    for (int t = 0; t < 8; ++t)
      s[t] = (red[0][jt][t] + red[1][jt][t] + red[2][jt][t] + red[3][jt][t]) *
             (1.0f / 32.0f);
    st8f(mcab + (size_t)(b * 8 + c) * 2048 + jt * 8, s);
  }
}

// ---------------- k1b: in-place P2 transform mc -> a2pre ----------------
__global__ void k1b_p2(float* __restrict__ mcab, const float* __restrict__ P2) {
  const int b = blockIdx.x >> 3;
  const int j = (blockIdx.x & 7) * 256 + threadIdx.x;
  float mc[8];
#pragma unroll
  for (int c = 0; c < 8; ++c) mc[c] = mcab[(size_t)(b * 8 + c) * 2048 + j];
  float a2[8];
#pragma unroll
  for (int o = 0; o < 8; ++o) {
    float s = 0.0f;
#pragma unroll
    for (int c = 0; c < 8; ++c) s = fmaf(P2[o * 8 + c], mc[c], s);
    a2[o] = 0.1f * s;
  }
#pragma unroll
  for (int o = 0; o < 8; ++o) mcab[(size_t)(b * 8 + o) * 2048 + j] = a2[o];
}

// ---------------- k2: main, fp16 pre-BN -> d_out low half ----------------
// grid 2048 = (b<<5)|m; 256 thr. (k,r): k=tid>>3, r=tid&7.
// LDS: qa5 holds q early, a5 late (aliased; q is in qf regs before a5 writes).
__global__ __launch_bounds__(256, 2) void k2_main(
    const float* __restrict__ A,
    const float* __restrict__ a2pre,
    const float* __restrict__ P1,
    const float* __restrict__ P3,
    const float* __restrict__ P4,
    const float* __restrict__ P5,
    const float* __restrict__ Wq,
    const float* __restrict__ Wk,
    float* __restrict__ outp,
    float* __restrict__ stats) {
  __shared__ float qa5[8 * 260];
  __shared__ float kb[8 * 260];
  __shared__ float vb[8 * 260];
  __shared__ float sred[64];

  const int tid = threadIdx.x;
  const int b = blockIdx.x >> 5;
  const int m = blockIdx.x & 31;
  const int k = tid >> 3;
  const int r = tid & 7;

  float acc[8][8];
  float acc3[8];
  float qv[8], kv[8], vv[8];
#pragma unroll
  for (int o = 0; o < 8; ++o) {
    acc3[o] = 0.0f;
#pragma unroll
    for (int t = 0; t < 8; ++t) acc[o][t] = 0.0f;
  }
#pragma unroll
  for (int t = 0; t < 8; ++t) { qv[t] = 0.0f; kv[t] = 0.0f; vv[t] = 0.0f; }

#pragma unroll
  for (int c = 0; c < 8; ++c) {
    float ar[8];
    ld8f(A + ((size_t)((b * 8 + c) * 32 + m) * 2048 + tid * 8), ar);
    float trc[8];
#pragma unroll
    for (int t = 0; t < 8; ++t) {
      float x = ar[t];
      x += __shfl_xor(x, 1, 64);
      x += __shfl_xor(x, 2, 64);
      x += __shfl_xor(x, 4, 64);
      trc[t] = x * 0.125f;
    }
    const float mtc = (ar[0] + ar[1] + ar[2] + ar[3] +
                       ar[4] + ar[5] + ar[6] + ar[7]) * 0.125f;
#pragma unroll
    for (int o = 0; o < 8; ++o) {
      const float w1 = P1[o * 8 + c];
      const float w4 = 0.5f * P4[o * 8 + c];
      acc3[o] = fmaf(0.1f * P3[o * 8 + c], mtc, acc3[o]);
#pragma unroll
      for (int t = 0; t < 8; ++t)
        acc[o][t] = fmaf(w1, ar[t], fmaf(w4, trc[t], acc[o][t]));
    }
    const float wq = Wq[r * 8 + c];
    const float wk = Wk[r * 8 + c];
    const float wv = P5[r * 8 + c];
#pragma unroll
    for (int t = 0; t < 8; ++t) {
      qv[t] = fmaf(wq, trc[t], qv[t]);
      kv[t] = fmaf(wk, trc[t], kv[t]);
      vv[t] = fmaf(wv, trc[t], vv[t]);
    }
  }

#pragma unroll
  for (int o = 0; o < 8; ++o) {
    float a2v[8];
    ld8f(a2pre + ((size_t)(b * 8 + o) * 2048 + tid * 8), a2v);
#pragma unroll
    for (int t = 0; t < 8; ++t) acc[o][t] += a2v[t] + acc3[o];
  }

  st8f(&qa5[r * 260 + k * 8], qv);
  st8f(&kb[r * 260 + k * 8], kv);
  st8f(&vb[r * 260 + k * 8], vv);
  __syncthreads();

  // Attention: thread = (o, kq, lo): 4 k-rows x 8 l-rows register tile
  {
    const int o = tid >> 5;
    const int kq = (tid >> 2) & 7;
    const int lo = tid & 3;
    float qf[4][8];
#pragma unroll
    for (int kl = 0; kl < 4; ++kl)
      ld8f(&qa5[o * 260 + (kq * 4 + kl) * 8], qf[kl]);
    __syncthreads();  // all qf loaded before qa5 is reused for a5

    float a5p[4][8];
#pragma unroll
    for (int kl = 0; kl < 4; ++kl)
#pragma unroll
      for (int t = 0; t < 8; ++t) a5p[kl][t] = 0.0f;

#pragma unroll
    for (int ll = 0; ll < 8; ++ll) {
      const int l = lo * 8 + ll;
      float krw[8];
      ld8f(&kb[o * 260 + l * 8], krw);
      float al[4];
#pragma unroll
      for (int kl = 0; kl < 4; ++kl) {
        float s = 0.0f;
#pragma unroll
        for (int t = 0; t < 8; ++t) s = fmaf(qf[kl][t], krw[t], s);
        al[kl] = fast_tanh(s * 0.125f);  // /NT
      }
      float vrw[8];
      ld8f(&vb[o * 260 + l * 8], vrw);
#pragma unroll
      for (int kl = 0; kl < 4; ++kl)
#pragma unroll
        for (int t = 0; t < 8; ++t)
          a5p[kl][t] = fmaf(al[kl], vrw[t], a5p[kl][t]);
    }
#pragma unroll
    for (int kl = 0; kl < 4; ++kl)
#pragma unroll
      for (int t = 0; t < 8; ++t) {
        float x = a5p[kl][t];
        x += __shfl_xor(x, 1, 64);
        x += __shfl_xor(x, 2, 64);
        a5p[kl][t] = x * 0.0625f;  // 2/Kd
      }
#pragma unroll
    for (int kl = 0; kl < 4; ++kl) {
      const float w0 = lo == 0 ? a5p[kl][0] : lo == 1 ? a5p[kl][2]
                      : lo == 2 ? a5p[kl][4] : a5p[kl][6];
      const float w1 = lo == 0 ? a5p[kl][1] : lo == 1 ? a5p[kl][3]
                      : lo == 2 ? a5p[kl][5] : a5p[kl][7];
      *(float2*)&qa5[o * 260 + (kq * 4 + kl) * 8 + lo * 2] = make_float2(w0, w1);
    }
  }
  __syncthreads();

  // Epilogue: +A5, ReLU, stats, store pre-BN fp16 at byte 2e of d_out
  float psum[8], psq[8];
#pragma unroll
  for (int o = 0; o < 8; ++o) { psum[o] = 0.0f; psq[o] = 0.0f; }
#pragma unroll
  for (int o = 0; o < 8; ++o) {
    float a5f[8];
    ld8f(&qa5[o * 260 + k * 8], a5f);
    float x8[8];
#pragma unroll
    for (int t = 0; t < 8; ++t) {
      float x = acc[o][t] + a5f[t];
      x = fmaxf(x, 0.0f);
      psum[o] += x;
      psq[o] = fmaf(x, x, psq[o]);
      x8[t] = x;
    }
    uint4 u;
    u.x = (u32)f2h(x8[0]) | ((u32)f2h(x8[1]) << 16);
    u.y = (u32)f2h(x8[2]) | ((u32)f2h(x8[3]) << 16);
    u.z = (u32)f2h(x8[4]) | ((u32)f2h(x8[5]) << 16);
    u.w = (u32)f2h(x8[6]) | ((u32)f2h(x8[7]) << 16);
    const size_t e = (size_t)((b * 8 + o) * 32 + m) * 2048 + tid * 8;
    *(uint4*)((char*)outp + 2 * e) = u;  // cached: re-read by k3 slices
  }
  // stats: wave butterfly -> LDS -> 16 global atomics
#pragma unroll
  for (int o = 0; o < 8; ++o) {
    float s = psum[o], q = psq[o];
#pragma unroll
    for (int mask = 32; mask >= 1; mask >>= 1) {
      s += __shfl_xor(s, mask, 64);
      q += __shfl_xor(q, mask, 64);
    }
    psum[o] = s; psq[o] = q;
  }
  const int lane = tid & 63;
  const int wid = tid >> 6;
  if (lane == 0) {
#pragma unroll
    for (int o = 0; o < 8; ++o) {
      sred[wid * 16 + o * 2] = psum[o];
      sred[wid * 16 + o * 2 + 1] = psq[o];
    }
  }
  __syncthreads();
  if (tid < 16) {
    float s = sred[tid] + sred[16 + tid] + sred[32 + tid] + sred[48 + tid];
    atomicAdd(&stats[tid], s);
  }
}

// ---------------- k3_copy: staging bytes [0,1MiB) -> ws tail buffer ----------------
__global__ void k3_copy(const uint4* __restrict__ src, uint4* __restrict__ dst) {
  const int i = blockIdx.x * 256 + threadIdx.x;  // 65536 uint4 = 1 MiB
  dst[i] = src[i];
}

// ---------------- k3_slice: normalize elements [ebase, ebase+n) ----------------
// src[e] = fp16 of element e (u16-indexed). For d_out staging src=(u16*)outp
// (byte 2e); for the ws tail src=ws16 (tail copied linearly).
__global__ void k3_slice(const u16* __restrict__ src, float* __restrict__ outp,
                         const float* __restrict__ stats,
                         const float* __restrict__ gamma,
                         const float* __restrict__ beta,
                         const u32 ebase) {
  const size_t e0 = (size_t)ebase + ((size_t)blockIdx.x * 256 + threadIdx.x) * 8;
  const int o = (int)(e0 >> 16) & 7;
  const float inv_n = 1.0f / 4194304.0f;
  const float mean = stats[o * 2] * inv_n;
  float var = stats[o * 2 + 1] * inv_n - mean * mean;
  var = fmaxf(var, 0.0f);
  const float inv = rsqrtf(var + 1e-5f);
  const float g = gamma[o] * inv;
  const float sh = beta[o] - mean * g;
  const uint4 u = *(const uint4*)(src + e0);
  float f[8];
  f[0] = h2f((u16)(u.x & 0xffffu)); f[1] = h2f((u16)(u.x >> 16));
  f[2] = h2f((u16)(u.y & 0xffffu)); f[3] = h2f((u16)(u.y >> 16));
  f[4] = h2f((u16)(u.z & 0xffffu)); f[5] = h2f((u16)(u.z >> 16));
  f[6] = h2f((u16)(u.w & 0xffffu)); f[7] = h2f((u16)(u.w >> 16));
#pragma unroll
  for (int t = 0; t < 8; ++t) f[t] = fmaf(f[t], g, sh);
  st8f_nt(outp + e0, f);
}

extern "C" void kernel_launch(void* const* d_in, const int* in_sizes, int n_in,
                              void* d_out, int out_size, void* d_ws, size_t ws_size,
                              hipStream_t stream) {
  const float* A  = (const float*)d_in[0];
  const float* P1 = (const float*)d_in[1];
  const float* P2 = (const float*)d_in[2];
  const float* P3 = (const float*)d_in[3];
  const float* P4 = (const float*)d_in[4];
  const float* P5 = (const float*)d_in[5];
  const float* Wq = (const float*)d_in[6];
  const float* Wk = (const float*)d_in[7];
  const float* gamma = (const float*)d_in[8];
  const float* beta  = (const float*)d_in[9];
  float* outp = (float*)d_out;

  float* stats = (float*)d_ws;
  float* mcab = (float*)((char*)d_ws + 256);  // 4 MB: mc -> a2pre -> fp16 tail

  hipLaunchKernelGGL(k1a_mmean, dim3(512), dim3(1024), 0, stream, A, mcab, stats);
  hipLaunchKernelGGL(k1b_p2, dim3(512), dim3(256), 0, stream, mcab, P2);
  hipLaunchKernelGGL(k2_main, dim3(2048), dim3(256), 0, stream,
                     A, mcab, P1, P3, P4, P5, Wq, Wk, outp, stats);

  // Tail staging relocation: fp16 of e<512Ki (bytes [0,1MiB)) -> mcab.
  // mcab (a2pre) is dead after k2; no later launch writes bytes [0,2MiB)
  // until the final slice.
  hipLaunchKernelGGL(k3_copy, dim3(256), dim3(256), 0, stream,
                     (const uint4*)outp, (uint4*)mcab);

  // Descending cascade: slice [n,2n) reads fp16 bytes [2n,4n), writes f32
  // [4n,8n) — disjoint; writes only clobber staging consumed by earlier slices.
  const u16* s16 = (const u16*)outp;
  for (u32 n = NTOT / 2; n >= 524288u; n >>= 1) {
    hipLaunchKernelGGL(k3_slice, dim3(n / 2048), dim3(256), 0, stream,
                       s16, outp, stats, gamma, beta, n);
  }
  // Final slice [0, 512Ki) from the ws copy.
  hipLaunchKernelGGL(k3_slice, dim3(256), dim3(256), 0, stream,
                     (const u16*)mcab, outp, stats, gamma, beta, 0u);
}

// Round 10
// 383.502 us; speedup vs baseline: 1.0362x; 1.0362x over previous
//
#include <hip/hip_runtime.h>
#include <hip/hip_fp16.h>

// layer_3d_dep_53300544143949 — MI355X (gfx950)
// B=64, C=8, O=8, M=32, K=32, NR=8, NT=8. All inputs and output FLOAT32.
// R13 = R12 + (a) f32x2-packed fold math (v_pk_fma_f32), (b) cascade 8->6 launches
// (tail = 2Mi elements = 4MiB in ws mcab, exactly the proven capacity).
// R12 post-mortem: cascade byte savings nullified by L3 (staging re-reads were
// already L3 hits in the single-k3 path); 8 launches cost ~15us. k2 LDS diet
// worked (127us). k2 is VALU/latency-mixed (VALU 49%, HBM 28%, Occ 21%).
//   k1a: m-mean reduce, block=(b,c), 1024 thr -> mc (ws, 4MB) + stats zero
//   k1b: in-place P2 transform mc -> a2pre
//   k2:  main fold (f32x2-packed) + attention. fp16 pre-BN at byte 2e of d_out.
//   k3_copy: staging bytes [0,4MiB) -> ws mcab (dead after k2)
//   k3_slice x4 (descending n=16Mi,8Mi,4Mi,2Mi): slice [n,2n) reads fp16 bytes
//        [2n,4n), writes f32 [4n,8n) — disjoint; then tail [0,2Mi) from ws.
// ws: [0,256) stats | [256, 256+4MiB) mc/a2pre (reused as fp16 tail staging)

using u16 = unsigned short;
using u32 = unsigned int;
typedef float f32x4 __attribute__((ext_vector_type(4)));
typedef float f32x2 __attribute__((ext_vector_type(2)));

#define NTOT 33554432u

__device__ __forceinline__ void ld8f(const float* p, float* f) {
  float4 a = *(const float4*)p;
  float4 b = *(const float4*)(p + 4);
  f[0] = a.x; f[1] = a.y; f[2] = a.z; f[3] = a.w;
  f[4] = b.x; f[5] = b.y; f[6] = b.z; f[7] = b.w;
}
__device__ __forceinline__ void ld8f2(const float* p, f32x2* f) {
  float4 a = *(const float4*)p;
  float4 b = *(const float4*)(p + 4);
  f[0] = f32x2{a.x, a.y}; f[1] = f32x2{a.z, a.w};
  f[2] = f32x2{b.x, b.y}; f[3] = f32x2{b.z, b.w};
}
__device__ __forceinline__ void st8f(float* p, const float* f) {
  *(float4*)p = make_float4(f[0], f[1], f[2], f[3]);
  *(float4*)(p + 4) = make_float4(f[4], f[5], f[6], f[7]);
}
__device__ __forceinline__ void st8f2(float* p, const f32x2* f) {
  *(float4*)p = make_float4(f[0][0], f[0][1], f[1][0], f[1][1]);
  *(float4*)(p + 4) = make_float4(f[2][0], f[2][1], f[3][0], f[3][1]);
}
__device__ __forceinline__ void st8f_nt(float* p, const float* f) {
  f32x4 a = {f[0], f[1], f[2], f[3]};
  f32x4 b = {f[4], f[5], f[6], f[7]};
  __builtin_nontemporal_store(a, (f32x4*)p);
  __builtin_nontemporal_store(b, (f32x4*)(p + 4));
}
__device__ __forceinline__ u16 f2h(float f) {
  __half h = __float2half_rn(f);
  return *(u16*)&h;
}
__device__ __forceinline__ float h2f(u16 x) {
  __half h = *(__half*)&x;
  return __half2float(h);
}
__device__ __forceinline__ float fast_tanh(float x) {
  float e = __expf(2.0f * x);
  return 1.0f - 2.0f / (e + 1.0f);
}

// ---------------- k1a: m-mean reduce (1024 thr, LDS reduce) ----------------
__global__ __launch_bounds__(1024) void k1a_mmean(
    const float* __restrict__ A, float* __restrict__ mcab,
    float* __restrict__ stats) {
  __shared__ float red[4][256][9];
  const int b = blockIdx.x >> 3;
  const int c = blockIdx.x & 7;
  const int tid = threadIdx.x;
  if (blockIdx.x == 0 && tid < 16) stats[tid] = 0.0f;
  const int mh = tid >> 8;
  const int jt = tid & 255;
  const float* base = A + (size_t)(b * 8 + c) * 65536 + (size_t)mh * 8 * 2048 + jt * 8;
  float acc[8];
#pragma unroll
  for (int t = 0; t < 8; ++t) acc[t] = 0.0f;
#pragma unroll
  for (int m = 0; m < 8; ++m) {
    float ar[8];
    ld8f(base + m * 2048, ar);
#pragma unroll
    for (int t = 0; t < 8; ++t) acc[t] += ar[t];
  }
#pragma unroll
  for (int t = 0; t < 8; ++t) red[mh][jt][t] = acc[t];
  __syncthreads();
  if (mh == 0) {
    float s[8];
#pragma unroll
    for (int t = 0; t < 8; ++t)
      s[t] = (red[0][jt][t] + red[1][jt][t] + red[2][jt][t] + red[3][jt][t]) *
             (1.0f / 32.0f);
    st8f(mcab + (size_t)(b * 8 + c) * 2048 + jt * 8, s);
  }
}

// ---------------- k1b: in-place P2 transform mc -> a2pre ----------------
__global__ void k1b_p2(float* __restrict__ mcab, const float* __restrict__ P2) {
  const int b = blockIdx.x >> 3;
  const int j = (blockIdx.x & 7) * 256 + threadIdx.x;
  float mc[8];
#pragma unroll
  for (int c = 0; c < 8; ++c) mc[c] = mcab[(size_t)(b * 8 + c) * 2048 + j];
  float a2[8];
#pragma unroll
  for (int o = 0; o < 8; ++o) {
    float s = 0.0f;
#pragma unroll
    for (int c = 0; c < 8; ++c) s = fmaf(P2[o * 8 + c], mc[c], s);
    a2[o] = 0.1f * s;
  }
#pragma unroll
  for (int o = 0; o < 8; ++o) mcab[(size_t)(b * 8 + o) * 2048 + j] = a2[o];
}

// ---------------- k2: main (packed fold), fp16 pre-BN -> d_out low half ------
// grid 2048 = (b<<5)|m; 256 thr. (k,r): k=tid>>3, r=tid&7.
__global__ __launch_bounds__(256, 2) void k2_main(
    const float* __restrict__ A,
    const float* __restrict__ a2pre,
    const float* __restrict__ P1,
    const float* __restrict__ P3,
    const float* __restrict__ P4,
    const float* __restrict__ P5,
    const float* __restrict__ Wq,
    const float* __restrict__ Wk,
    float* __restrict__ outp,
    float* __restrict__ stats) {
  __shared__ float qa5[8 * 260];
  __shared__ float kb[8 * 260];
  __shared__ float vb[8 * 260];
  __shared__ float sred[64];

  const int tid = threadIdx.x;
  const int b = blockIdx.x >> 5;
  const int m = blockIdx.x & 31;
  const int k = tid >> 3;
  const int r = tid & 7;

  f32x2 acc2[8][4];
  float acc3[8];
  f32x2 qv2[4], kv2[4], vv2[4];
#pragma unroll
  for (int o = 0; o < 8; ++o) {
    acc3[o] = 0.0f;
#pragma unroll
    for (int p = 0; p < 4; ++p) acc2[o][p] = f32x2{0.0f, 0.0f};
  }
#pragma unroll
  for (int p = 0; p < 4; ++p) {
    qv2[p] = f32x2{0.0f, 0.0f};
    kv2[p] = f32x2{0.0f, 0.0f};
    vv2[p] = f32x2{0.0f, 0.0f};
  }

#pragma unroll
  for (int c = 0; c < 8; ++c) {
    f32x2 ar2[4];
    ld8f2(A + ((size_t)((b * 8 + c) * 32 + m) * 2048 + tid * 8), ar2);
    f32x2 trc2[4];
#pragma unroll
    for (int t = 0; t < 8; ++t) {
      float x = ar2[t >> 1][t & 1];
      x += __shfl_xor(x, 1, 64);
      x += __shfl_xor(x, 2, 64);
      x += __shfl_xor(x, 4, 64);
      trc2[t >> 1][t & 1] = x * 0.125f;
    }
    const float mtc = (ar2[0][0] + ar2[0][1] + ar2[1][0] + ar2[1][1] +
                       ar2[2][0] + ar2[2][1] + ar2[3][0] + ar2[3][1]) * 0.125f;
#pragma unroll
    for (int o = 0; o < 8; ++o) {
      const float w1 = P1[o * 8 + c];
      const float w4 = 0.5f * P4[o * 8 + c];
      acc3[o] = fmaf(0.1f * P3[o * 8 + c], mtc, acc3[o]);
      const f32x2 w1v = {w1, w1};
      const f32x2 w4v = {w4, w4};
#pragma unroll
      for (int p = 0; p < 4; ++p)
        acc2[o][p] = w1v * ar2[p] + (w4v * trc2[p] + acc2[o][p]);
    }
    const float wq = Wq[r * 8 + c];
    const float wk = Wk[r * 8 + c];
    const float wv = P5[r * 8 + c];
    const f32x2 wqv = {wq, wq};
    const f32x2 wkv = {wk, wk};
    const f32x2 wvv = {wv, wv};
#pragma unroll
    for (int p = 0; p < 4; ++p) {
      qv2[p] = wqv * trc2[p] + qv2[p];
      kv2[p] = wkv * trc2[p] + kv2[p];
      vv2[p] = wvv * trc2[p] + vv2[p];
    }
  }

  // A2 (precomputed) + A3 broadcast
#pragma unroll
  for (int o = 0; o < 8; ++o) {
    f32x2 a2v2[4];
    ld8f2(a2pre + ((size_t)(b * 8 + o) * 2048 + tid * 8), a2v2);
    const f32x2 a3v = {acc3[o], acc3[o]};
#pragma unroll
    for (int p = 0; p < 4; ++p) acc2[o][p] = acc2[o][p] + a2v2[p] + a3v;
  }

  st8f2(&qa5[r * 260 + k * 8], qv2);
  st8f2(&kb[r * 260 + k * 8], kv2);
  st8f2(&vb[r * 260 + k * 8], vv2);
  __syncthreads();

  // Attention: thread = (o, kq, lo): 4 k-rows x 8 l-rows register tile
  {
    const int o = tid >> 5;
    const int kq = (tid >> 2) & 7;
    const int lo = tid & 3;
    float qf[4][8];
#pragma unroll
    for (int kl = 0; kl < 4; ++kl)
      ld8f(&qa5[o * 260 + (kq * 4 + kl) * 8], qf[kl]);
    __syncthreads();  // all qf loaded before qa5 is reused for a5

    float a5p[4][8];
#pragma unroll
    for (int kl = 0; kl < 4; ++kl)
#pragma unroll
      for (int t = 0; t < 8; ++t) a5p[kl][t] = 0.0f;

#pragma unroll
    for (int ll = 0; ll < 8; ++ll) {
      const int l = lo * 8 + ll;
      float krw[8];
      ld8f(&kb[o * 260 + l * 8], krw);
      float al[4];
#pragma unroll
      for (int kl = 0; kl < 4; ++kl) {
        float s = 0.0f;
#pragma unroll
        for (int t = 0; t < 8; ++t) s = fmaf(qf[kl][t], krw[t], s);
        al[kl] = fast_tanh(s * 0.125f);  // /NT
      }
      float vrw[8];
      ld8f(&vb[o * 260 + l * 8], vrw);
#pragma unroll
      for (int kl = 0; kl < 4; ++kl)
#pragma unroll
        for (int t = 0; t < 8; ++t)
          a5p[kl][t] = fmaf(al[kl], vrw[t], a5p[kl][t]);
    }
#pragma unroll
    for (int kl = 0; kl < 4; ++kl)
#pragma unroll
      for (int t = 0; t < 8; ++t) {
        float x = a5p[kl][t];
        x += __shfl_xor(x, 1, 64);
        x += __shfl_xor(x, 2, 64);
        a5p[kl][t] = x * 0.0625f;  // 2/Kd
      }
#pragma unroll
    for (int kl = 0; kl < 4; ++kl) {
      const float w0 = lo == 0 ? a5p[kl][0] : lo == 1 ? a5p[kl][2]
                      : lo == 2 ? a5p[kl][4] : a5p[kl][6];
      const float w1 = lo == 0 ? a5p[kl][1] : lo == 1 ? a5p[kl][3]
                      : lo == 2 ? a5p[kl][5] : a5p[kl][7];
      *(float2*)&qa5[o * 260 + (kq * 4 + kl) * 8 + lo * 2] = make_float2(w0, w1);
    }
  }
  __syncthreads();

  // Epilogue: +A5, ReLU, stats, store pre-BN fp16 at byte 2e of d_out
  float psum[8], psq[8];
#pragma unroll
  for (int o = 0; o < 8; ++o) { psum[o] = 0.0f; psq[o] = 0.0f; }
#pragma unroll
  for (int o = 0; o < 8; ++o) {
    float a5f[8];
    ld8f(&qa5[o * 260 + k * 8], a5f);
    float x8[8];
#pragma unroll
    for (int t = 0; t < 8; ++t) {
      float x = acc2[o][t >> 1][t & 1] + a5f[t];
      x = fmaxf(x, 0.0f);
      psum[o] += x;
      psq[o] = fmaf(x, x, psq[o]);
      x8[t] = x;
    }
    uint4 u;
    u.x = (u32)f2h(x8[0]) | ((u32)f2h(x8[1]) << 16);
    u.y = (u32)f2h(x8[2]) | ((u32)f2h(x8[3]) << 16);
    u.z = (u32)f2h(x8[4]) | ((u32)f2h(x8[5]) << 16);
    u.w = (u32)f2h(x8[6]) | ((u32)f2h(x8[7]) << 16);
    const size_t e = (size_t)((b * 8 + o) * 32 + m) * 2048 + tid * 8;
    *(uint4*)((char*)outp + 2 * e) = u;  // cached: re-read by k3 slices
  }
  // stats: wave butterfly -> LDS -> 16 global atomics
#pragma unroll
  for (int o = 0; o < 8; ++o) {
    float s = psum[o], q = psq[o];
#pragma unroll
    for (int mask = 32; mask >= 1; mask >>= 1) {
      s += __shfl_xor(s, mask, 64);
      q += __shfl_xor(q, mask, 64);
    }
    psum[o] = s; psq[o] = q;
  }
  const int lane = tid & 63;
  const int wid = tid >> 6;
  if (lane == 0) {
#pragma unroll
    for (int o = 0; o < 8; ++o) {
      sred[wid * 16 + o * 2] = psum[o];
      sred[wid * 16 + o * 2 + 1] = psq[o];
    }
  }
  __syncthreads();
  if (tid < 16) {
    float s = sred[tid] + sred[16 + tid] + sred[32 + tid] + sred[48 + tid];
    atomicAdd(&stats[tid], s);
  }
}

// ---------------- k3_copy: staging bytes [0,4MiB) -> ws tail buffer ----------
__global__ void k3_copy(const uint4* __restrict__ src, uint4* __restrict__ dst) {
  const int i = blockIdx.x * 256 + threadIdx.x;  // 262144 uint4 = 4 MiB
  dst[i] = src[i];
}

// ---------------- k3_slice: normalize elements [ebase, ebase+n) --------------
__global__ void k3_slice(const u16* __restrict__ src, float* __restrict__ outp,
                         const float* __restrict__ stats,
                         const float* __restrict__ gamma,
                         const float* __restrict__ beta,
                         const u32 ebase) {
  const size_t e0 = (size_t)ebase + ((size_t)blockIdx.x * 256 + threadIdx.x) * 8;
  const int o = (int)(e0 >> 16) & 7;
  const float inv_n = 1.0f / 4194304.0f;
  const float mean = stats[o * 2] * inv_n;
  float var = stats[o * 2 + 1] * inv_n - mean * mean;
  var = fmaxf(var, 0.0f);
  const float inv = rsqrtf(var + 1e-5f);
  const float g = gamma[o] * inv;
  const float sh = beta[o] - mean * g;
  const uint4 u = *(const uint4*)(src + e0);
  float f[8];
  f[0] = h2f((u16)(u.x & 0xffffu)); f[1] = h2f((u16)(u.x >> 16));
  f[2] = h2f((u16)(u.y & 0xffffu)); f[3] = h2f((u16)(u.y >> 16));
  f[4] = h2f((u16)(u.z & 0xffffu)); f[5] = h2f((u16)(u.z >> 16));
  f[6] = h2f((u16)(u.w & 0xffffu)); f[7] = h2f((u16)(u.w >> 16));
#pragma unroll
  for (int t = 0; t < 8; ++t) f[t] = fmaf(f[t], g, sh);
  st8f_nt(outp + e0, f);
}

extern "C" void kernel_launch(void* const* d_in, const int* in_sizes, int n_in,
                              void* d_out, int out_size, void* d_ws, size_t ws_size,
                              hipStream_t stream) {
  const float* A  = (const float*)d_in[0];
  const float* P1 = (const float*)d_in[1];
  const float* P2 = (const float*)d_in[2];
  const float* P3 = (const float*)d_in[3];
  const float* P4 = (const float*)d_in[4];
  const float* P5 = (const float*)d_in[5];
  const float* Wq = (const float*)d_in[6];
  const float* Wk = (const float*)d_in[7];
  const float* gamma = (const float*)d_in[8];
  const float* beta  = (const float*)d_in[9];
  float* outp = (float*)d_out;

  float* stats = (float*)d_ws;
  float* mcab = (float*)((char*)d_ws + 256);  // 4 MiB: mc -> a2pre -> fp16 tail

  hipLaunchKernelGGL(k1a_mmean, dim3(512), dim3(1024), 0, stream, A, mcab, stats);
  hipLaunchKernelGGL(k1b_p2, dim3(512), dim3(256), 0, stream, mcab, P2);
  hipLaunchKernelGGL(k2_main, dim3(2048), dim3(256), 0, stream,
                     A, mcab, P1, P3, P4, P5, Wq, Wk, outp, stats);

  // Tail staging relocation: fp16 of e<2Mi (bytes [0,4MiB)) -> mcab (dead
  // after k2; exactly fits the proven >=4MiB+256 ws).
  hipLaunchKernelGGL(k3_copy, dim3(1024), dim3(256), 0, stream,
                     (const uint4*)outp, (uint4*)mcab);

  // Descending cascade: slice [n,2n) reads fp16 bytes [2n,4n), writes f32
  // [4n,8n) — disjoint; writes only clobber staging consumed by earlier slices.
  const u16* s16 = (const u16*)outp;
  for (u32 n = NTOT / 2; n >= 2097152u; n >>= 1) {
    hipLaunchKernelGGL(k3_slice, dim3(n / 2048), dim3(256), 0, stream,
                       s16, outp, stats, gamma, beta, n);
  }
  // Final slice [0, 2Mi) from the ws copy (writes f32 bytes [0,8MiB); its
  // reads come from ws, so clobbering outp staging [0,4MiB) is safe).
  hipLaunchKernelGGL(k3_slice, dim3(1024), dim3(256), 0, stream,
                     (const u16*)mcab, outp, stats, gamma, beta, 0u);
}